// Round 7
// baseline (197.821 us; speedup 1.0000x reference)
//
#include <hip/hip_runtime.h>
#include <math.h>

// Rolling stats: W=64 window over (N=262144, F=32) fp32, stride 1, VALID.
// Out row t (t < N-63): [mean(32) | std(32) | min(32) | max(32) | sum(32)].
//
// R7: software-pipelined persistent tiles.
//  - Block = 256 threads = 8 chunks x 32 cols; tile = 128 output rows,
//    stages 192 input rows (24576 B LDS, single buffer).
//  - Each block owns 2 CONSECUTIVE tiles (halo rows L2-hot for tile 2).
//    Pipeline: prefetch tile t+1 into registers (6 float4/thread) BEFORE
//    computing tile t -> global-load latency hides under compute, and
//    stores of tile t interleave with loads of t+1 in the memory pipe.
//  - __launch_bounds__(256,3): cap 170 VGPR, est. use ~110. R6 lesson:
//    a (256,4)/128-VGPR cap spilled and corrupted output under graph
//    replay — never cap below demand.
//  - Banks: dword idx = row*32 + c -> bank c; lanes 0..31 distinct banks,
//    half-wave 2-way alias free (m136). Zero conflicts.
//  - Stores: each instr = 2 aligned full 128B segments (row = 5*128B).

#define WINW 64
#define RCH 16
#define NF 32
#define CHUNKS 8
#define TROWS (CHUNKS * RCH)   // 128 output rows per tile
#define SROWS (TROWS + WINW)   // 192 input rows staged
#define FVT (SROWS * NF / 4 / 256)  // 6 float4 per thread
#define TILES_PER_BLK 2

__global__ __launch_bounds__(256, 3) void rolling_stats_kernel(
    const float* __restrict__ x, float* __restrict__ out, int N, int T_out,
    int ntiles) {
  __shared__ float tile[SROWS * NF];  // 24576 B
  float4* tv = (float4*)tile;
  const float4* xv = (const float4*)x;

  int tid = (int)threadIdx.x;
  int c = tid & (NF - 1);
  int lr0 = (tid >> 5) * RCH;

  float4 g[FVT];
  int t = blockIdx.x * TILES_PER_BLK;  // first tile of this block

  // Prefetch tile t.
  {
    int base = t * TROWS;
#pragma unroll
    for (int i = 0; i < FVT; ++i) {
      int f = i * 256 + tid;
      int gr = base + (f >> 3);
      gr = gr < N ? gr : N - 1;  // clamp (tail tile; stores guarded)
      g[i] = xv[(size_t)gr * (NF / 4) + (f & 7)];
    }
  }

#pragma unroll
  for (int it = 0; it < TILES_PER_BLK; ++it, ++t) {
    if (t >= ntiles) break;
    // Drain previous tile's LDS readers, then publish prefetched tile.
    __syncthreads();
#pragma unroll
    for (int i = 0; i < FVT; ++i) tv[i * 256 + tid] = g[i];

    // Prefetch next tile (issued before compute -> latency hidden).
    if (it + 1 < TILES_PER_BLK && t + 1 < ntiles) {
      int base = (t + 1) * TROWS;
#pragma unroll
      for (int i = 0; i < FVT; ++i) {
        int f = i * 256 + tid;
        int gr = base + (f >> 3);
        gr = gr < N ? gr : N - 1;
        g[i] = xv[(size_t)gr * (NF / 4) + (f & 7)];
      }
    }
    __syncthreads();

    // --- Compute 16 outputs for (column c, rows t*TROWS+lr0 ...). ---
    const float* tc = tile + c;
    int t0 = t * TROWS + lr0;

    float smin[RCH], smax[RCH];
    float ssum = 0.f, ssq = 0.f;
    float rmin = INFINITY, rmax = -INFINITY;

#pragma unroll
    for (int j = WINW - 1; j >= RCH; --j) {
      float a = tc[(lr0 + j) * NF];
      rmin = fminf(rmin, a);
      rmax = fmaxf(rmax, a);
      ssum += a;
      ssq = fmaf(a, a, ssq);
    }
#pragma unroll
    for (int j = RCH - 1; j >= 0; --j) {
      float a = tc[(lr0 + j) * NF];
      rmin = fminf(rmin, a);
      rmax = fmaxf(rmax, a);
      ssum += a;
      ssq = fmaf(a, a, ssq);
      smin[j] = rmin;
      smax[j] = rmax;
    }

    float pmin = INFINITY, pmax = -INFINITY;
    float wsum = ssum, wsq = ssq;
    float* o = out + (size_t)t0 * (5 * NF) + c;
#pragma unroll
    for (int j = 0; j < RCH; ++j) {
      if (j > 0) {
        float bnew = tc[(lr0 + WINW - 1 + j) * NF];  // max lr 190 < 192
        float aold = tc[(lr0 + j - 1) * NF];
        pmin = fminf(pmin, bnew);
        pmax = fmaxf(pmax, bnew);
        wsum += bnew - aold;
        wsq = fmaf(bnew, bnew, wsq);
        wsq = fmaf(-aold, aold, wsq);
      }
      if (t0 + j < T_out) {
        float wmin = fminf(smin[j], pmin);
        float wmax = fmaxf(smax[j], pmax);
        float mean = wsum * 0.015625f;                   // /64
        float var = fmaf(-mean, mean, wsq * 0.015625f);  // E[x^2]-E[x]^2
        var = fmaxf(var, 0.f);
        float sd = sqrtf(var);
        float* orow = o + (size_t)j * (5 * NF);
        orow[0 * NF] = mean;
        orow[1 * NF] = sd;
        orow[2 * NF] = wmin;
        orow[3 * NF] = wmax;
        orow[4 * NF] = wsum;
      }
    }
  }
}

extern "C" void kernel_launch(void* const* d_in, const int* in_sizes, int n_in,
                              void* d_out, int out_size, void* d_ws,
                              size_t ws_size, hipStream_t stream) {
  const float* x = (const float*)d_in[0];
  float* out = (float*)d_out;
  int N = in_sizes[0] / NF;    // 262144 rows
  int T_out = N - (WINW - 1);  // 262081 output rows
  int ntiles = (T_out + TROWS - 1) / TROWS;                 // 2048
  int nblocks = (ntiles + TILES_PER_BLK - 1) / TILES_PER_BLK;  // 1024
  rolling_stats_kernel<<<nblocks, 256, 0, stream>>>(x, out, N, T_out, ntiles);
}

// Round 8
// 191.419 us; speedup vs baseline: 1.0334x; 1.0334x over previous
//
#include <hip/hip_runtime.h>
#include <math.h>

// Rolling stats: W=64 window over (N=262144, F=32) fp32, stride 1, VALID.
// Out row t (t < N-63): [mean(32) | std(32) | min(32) | max(32) | sum(32)].
//
// R8 = R5 (best, 183.9 us) + nontemporal stores. R7's register-prefetch
// pipeline regressed (197.8) and is reverted.
//  - Block = 256 threads = 8 chunks x 32 columns, covers 256 output rows
//    (RCH=32), stages 320 input rows (40960 B LDS, float4 coalesced).
//    Overlap re-fetch 1.25x.
//  - Per thread (column c, 32 output rows): reverse suffix min/max scan of
//    the first window into register arrays; outgoing-row values ox[31]
//    cached in registers during the same scan. Forward pass: O(1) prefix
//    min/max + sliding sum/sumsq from LDS.
//  - __launch_bounds__(256,3): R6 showed a 128-VGPR cap spills and
//    corrupts under graph replay; demand is ~140-160, cap 170.
//  - Banks: dword idx = row*32 + c -> bank c; lanes 0..31 distinct banks,
//    half-wave 2-way alias free (m136). Zero conflicts.
//  - Stores: nontemporal (write-once 168 MB; keep L2 for the input halo
//    shared between neighbor blocks). Each instr = 2 full 128B segments.

#define WINW 64
#define RCH 32
#define NF 32
#define CHUNKS_PER_BLK 8
#define ROWS_PER_BLK (CHUNKS_PER_BLK * RCH)  // 256 output rows
#define STAGE_ROWS (ROWS_PER_BLK + WINW)     // 320 input rows staged

__global__ __launch_bounds__(256, 3) void rolling_stats_kernel(
    const float* __restrict__ x, float* __restrict__ out, int N, int T_out) {
  __shared__ float tile[STAGE_ROWS * NF];  // 40960 B

  int t0_blk = blockIdx.x * ROWS_PER_BLK;

  // --- Stage: 320 rows x 32 floats = 2560 float4, 10 per thread. ---
  const float4* xv = (const float4*)x;  // row r = 8 float4s
  float4* tv = (float4*)tile;
#pragma unroll
  for (int it = 0; it < (STAGE_ROWS * NF / 4) / 256; ++it) {
    int f = it * 256 + (int)threadIdx.x;
    int r = f >> 3;            // local row
    int gr = t0_blk + r;
    gr = gr < N ? gr : N - 1;  // clamp (tail block; stores guarded)
    tv[f] = xv[(size_t)gr * (NF / 4) + (f & 7)];
  }
  __syncthreads();

  // --- Per-thread sliding window over LDS. ---
  int c = (int)threadIdx.x & (NF - 1);
  int lr0 = ((int)threadIdx.x >> 5) * RCH;  // local first output row
  int t0 = t0_blk + lr0;
  const float* tc = tile + c;

  float smin[RCH], smax[RCH];  // suffix min/max of first window
  float ox[RCH - 1];           // outgoing rows lr0 .. lr0+30 (reg-cached)
  float ssum = 0.f, ssq = 0.f;
  float rmin = INFINITY, rmax = -INFINITY;

  // Pass 1: reverse scan of first window rows lr0+63 .. lr0.
#pragma unroll
  for (int j = WINW - 1; j >= RCH; --j) {
    float a = tc[(lr0 + j) * NF];
    rmin = fminf(rmin, a);
    rmax = fmaxf(rmax, a);
    ssum += a;
    ssq = fmaf(a, a, ssq);
  }
#pragma unroll
  for (int j = RCH - 1; j >= 0; --j) {
    float a = tc[(lr0 + j) * NF];
    rmin = fminf(rmin, a);
    rmax = fmaxf(rmax, a);
    ssum += a;
    ssq = fmaf(a, a, ssq);
    smin[j] = rmin;
    smax[j] = rmax;
    if (j < RCH - 1) ox[j] = a;  // constant predicate after unroll
  }

  // Pass 2: forward over the chunk's 32 outputs.
  float pmin = INFINITY, pmax = -INFINITY;
  float wsum = ssum, wsq = ssq;
  float* o = out + (size_t)t0 * (5 * NF) + c;
#pragma unroll
  for (int j = 0; j < RCH; ++j) {
    if (j > 0) {
      float bnew = tc[(lr0 + WINW - 1 + j) * NF];  // incoming (max lr 318)
      float aold = ox[j - 1];                      // outgoing (registers)
      pmin = fminf(pmin, bnew);
      pmax = fmaxf(pmax, bnew);
      wsum += bnew - aold;
      wsq = fmaf(bnew, bnew, wsq);
      wsq = fmaf(-aold, aold, wsq);
    }
    if (t0 + j < T_out) {
      float wmin = fminf(smin[j], pmin);
      float wmax = fmaxf(smax[j], pmax);
      float mean = wsum * 0.015625f;                   // /64
      float var = fmaf(-mean, mean, wsq * 0.015625f);  // E[x^2]-E[x]^2
      var = fmaxf(var, 0.f);
      float sd = sqrtf(var);
      float* orow = o + (size_t)j * (5 * NF);
      __builtin_nontemporal_store(mean, &orow[0 * NF]);
      __builtin_nontemporal_store(sd, &orow[1 * NF]);
      __builtin_nontemporal_store(wmin, &orow[2 * NF]);
      __builtin_nontemporal_store(wmax, &orow[3 * NF]);
      __builtin_nontemporal_store(wsum, &orow[4 * NF]);
    }
  }
}

extern "C" void kernel_launch(void* const* d_in, const int* in_sizes, int n_in,
                              void* d_out, int out_size, void* d_ws,
                              size_t ws_size, hipStream_t stream) {
  const float* x = (const float*)d_in[0];
  float* out = (float*)d_out;
  int N = in_sizes[0] / NF;    // 262144 rows
  int T_out = N - (WINW - 1);  // 262081 output rows
  int nblocks = (T_out + ROWS_PER_BLK - 1) / ROWS_PER_BLK;  // 1024
  rolling_stats_kernel<<<nblocks, 256, 0, stream>>>(x, out, N, T_out);
}